// Round 16
// baseline (10328.592 us; speedup 1.0000x reference)
//
#include <hip/hip_runtime.h>
#include <hip/hip_bf16.h>

#define BB 64
#define TT 2048
#define HH 256
#define H4 1024
#define NC 10
#define CH 64            // steps per chunk
#define NCH (TT / CH)    // 32 chunks
#define NR 4             // gx ring slots

typedef _Float16 half2v __attribute__((ext_vector_type(2)));
typedef _Float16 half8  __attribute__((ext_vector_type(8)));
typedef float    f32x4  __attribute__((ext_vector_type(4)));

struct __align__(128) Line { unsigned v; unsigned pad[31]; };

__device__ __forceinline__ float fsig_(float x) {
    return __fdividef(1.f, 1.f + __expf(-x));
}
__device__ __forceinline__ float ftanh_(float x) {
    return 1.f - __fdividef(2.f, __expf(2.f * x) + 1.f);
}

__device__ __forceinline__ float fdot2_(unsigned wu, half2v hv, float acc) {
#if __has_builtin(__builtin_amdgcn_fdot2)
    return __builtin_amdgcn_fdot2(__builtin_bit_cast(half2v, wu), hv, acc, false);
#else
    half2v w = __builtin_bit_cast(half2v, wu);
    return acc + (float)w[0] * (float)hv[0] + (float)w[1] * (float)hv[1];
#endif
}

// wave-0 parallel poll of 64 flags; one acquire fence; releases whole WG.
__device__ __forceinline__ void wait_flags(Line* f, unsigned target, int tid) {
    if (tid < 64) {
        while (true) {
            unsigned v = __hip_atomic_load(&f[tid].v, __ATOMIC_RELAXED,
                                           __HIP_MEMORY_SCOPE_AGENT);
            if (__all(v >= target)) break;
            __builtin_amdgcn_s_sleep(2);
        }
        if (tid == 0)
            __builtin_amdgcn_fence(__ATOMIC_ACQUIRE, "agent");
    }
    __syncthreads();
}

// ---------------------------------------------------------------------------
__global__ void f32_to_f16(const float* __restrict__ in,
                           _Float16* __restrict__ out, int n8)
{
    int i = blockIdx.x * 256 + threadIdx.x;
    if (i >= n8) return;
    float4 v0 = ((const float4*)in)[2 * i];
    float4 v1 = ((const float4*)in)[2 * i + 1];
    half8 h;
    h[0] = (_Float16)v0.x; h[1] = (_Float16)v0.y;
    h[2] = (_Float16)v0.z; h[3] = (_Float16)v0.w;
    h[4] = (_Float16)v1.x; h[5] = (_Float16)v1.y;
    h[6] = (_Float16)v1.z; h[7] = (_Float16)v1.w;
    ((half8*)out)[i] = h;
}

// ---------------------------------------------------------------------------
__global__ void prep_w(const float* __restrict__ W, uint4* __restrict__ out)
{
    const int k2 = blockIdx.x, t = threadIdx.x;
    unsigned q4[4];
#pragma unroll
    for (int q = 0; q < 4; q++) {
        const float* wr = W + (size_t)(q * 256 + t) * 256 + 2 * k2;
        union { _Float16 h[2]; unsigned u; } cv;
        cv.h[0] = (_Float16)wr[0];
        cv.h[1] = (_Float16)wr[1];
        q4[q] = cv.u;
    }
    out[(size_t)k2 * 256 + t] = make_uint4(q4[0], q4[1], q4[2], q4[3]);
}

// ---------------------------------------------------------------------------
// 4-role pipelined persistent kernel, 256 WGs x 512 threads:
//  role0 wg[0,64)   : L1 recurrence  role1 wg[64,128) : gemm1 (x16*Wih0)
//  role2 wg[128,192): gemm2 (h1c*Wih1)  role3 wg[192,256): L2 recurrence
// Rec engine: FULL 64-quad register/AGPR weight residency (volatile loads;
// R13/14 precedent: allocator AGPR-backs, zero scratch; cap 256V+256A).
// LDS per step: only 16 h-broadcast b128 reads + pre exchange.
// ---------------------------------------------------------------------------
__global__ __launch_bounds__(512, 1)
void lstm_pipe(const _Float16* __restrict__ x16,
               const _Float16* __restrict__ w16a, const _Float16* __restrict__ w16b,
               const float* __restrict__ bih0, const float* __restrict__ bhh0,
               const float* __restrict__ bih1, const float* __restrict__ bhh1,
               const uint4* __restrict__ wpk0, const uint4* __restrict__ wpk1,
               _Float16* __restrict__ gx1r, _Float16* __restrict__ gx2r,
               _Float16* __restrict__ h1c,
               float* __restrict__ hs1, float* __restrict__ cs1,
               float* __restrict__ hs2, float* __restrict__ cs2,
               Line* __restrict__ fG1, Line* __restrict__ fL1,
               Line* __restrict__ fG2, Line* __restrict__ fL2)
{
    __shared__ __align__(16) unsigned char pool[1088 + 4096];
    _Float16* hlb = (_Float16*)pool;
    float*    pre = (float*)(pool + 1088);

    const int wg = blockIdx.x, tid = threadIdx.x;
    const int role = wg >> 6, sub = wg & 63;

    if (role == 1 || role == 2) {
        // ---------------- gemm worker ----------------
        const bool isG2 = (role == 2);
        const _Float16* A  = isG2 ? h1c  : x16;
        const _Float16* Wm = isG2 ? w16b : w16a;
        const float* b1 = isG2 ? bih1 : bih0;
        const float* b2 = isG2 ? bhh1 : bhh0;
        _Float16* outr  = isG2 ? gx2r : gx1r;
        Line* fOut      = isG2 ? fG2  : fG1;

        const int v = tid >> 6, lane = tid & 63;
        const int lrow = lane & 15, lkg = lane >> 4;
        const int rquad = v & 3, nqh = v >> 2;

        for (int c = 0; c < NCH; c++) {
            if (isG2) {
                wait_flags(fL1, (unsigned)(c + 1), tid);
                if (c >= NR) wait_flags(fL2, (unsigned)(c - (NR - 1)), tid);
            } else {
                if (c >= NR) wait_flags(fL1, (unsigned)(c - (NR - 1)), tid);
            }
            const int tc = c * CH + sub;
            const int slot = c % NR;
            const _Float16* arow =
                A + ((size_t)(rquad * 16 + lrow) * TT + tc) * 256 + lkg * 8;
#pragma unroll
            for (int pass = 0; pass < 2; pass++) {
                const int n0 = (nqh * 2 + pass) * 256;
                const _Float16* wrow = Wm + (size_t)(n0 + lrow) * 256 + lkg * 8;
                f32x4 acc[16];
#pragma unroll
                for (int j = 0; j < 16; j++) acc[j] = (f32x4)(0.f);
#pragma unroll
                for (int k0 = 0; k0 < 256; k0 += 32) {
                    half8 a = *(const half8*)(arow + k0);
#pragma unroll
                    for (int j = 0; j < 16; j++) {
                        half8 bf = *(const half8*)(wrow + (size_t)j * 16 * 256 + k0);
                        acc[j] = __builtin_amdgcn_mfma_f32_16x16x32_f16(a, bf, acc[j], 0, 0, 0);
                    }
                }
                const int bout = rquad * 16 + lkg * 4;
#pragma unroll
                for (int j = 0; j < 16; j++) {
                    int n = n0 + j * 16 + lrow;
                    float bsum = b1[n] + b2[n];
#pragma unroll
                    for (int r = 0; r < 4; r++) {
                        outr[((size_t)(slot * CH + sub) * BB + bout + r) * H4 + n] =
                            (_Float16)(acc[j][r] + bsum);
                    }
                }
            }
            __syncthreads();   // drain this WG's stores
            if (tid == 0) {
                __builtin_amdgcn_fence(__ATOMIC_RELEASE, "agent");
                __hip_atomic_store(&fOut[sub].v, (unsigned)(c + 1),
                                   __ATOMIC_RELAXED, __HIP_MEMORY_SCOPE_AGENT);
            }
        }
        return;
    }

    // ---------------- recurrence (role 0 = L1, role 3 = L2) ----------------
    const bool isL2 = (role == 3);
    const uint4* wpk = isL2 ? wpk1 : wpk0;
    const _Float16* gxr = isL2 ? gx2r : gx1r;
    float* hst = isL2 ? hs2 : hs1;
    float* cst = isL2 ? cs2 : cs1;
    Line* fIn  = isL2 ? fG2 : fG1;
    Line* fOut = isL2 ? fL2 : fL1;
    const int b = sub;
    const int tau = tid & 255, hh = tid >> 8;

    // FULL register/AGPR weight residency: 64 quads (k2 = hh*64 + r), volatile
    uint4 w4[64];
    {
        const volatile unsigned* wv = (const volatile unsigned*)wpk;
#pragma unroll
        for (int r = 0; r < 64; r++) {
            size_t base = ((size_t)(hh * 64 + r) * 256 + tau) * 4;
            w4[r].x = wv[base + 0];
            w4[r].y = wv[base + 1];
            w4[r].z = wv[base + 2];
            w4[r].w = wv[base + 3];
        }
    }

    float c_ = 0.f, lastH = 0.f;
    if (hh == 0) {
        c_ = cst[b * HH + tau];
        lastH = hst[b * HH + tau];
        hlb[tau] = (_Float16)lastH;
    }
    __syncthreads();

    int p = 0;
    for (int ch = 0; ch < NCH; ch++) {
        wait_flags(fIn, (unsigned)(ch + 1), tid);
        const _Float16* gsl = gxr + (size_t)(ch % NR) * CH * BB * H4
                            + (size_t)b * H4 + tau;
        float gc0 = 0.f, gc1 = 0.f, gc2 = 0.f, gc3 = 0.f;
        if (hh == 1) {
            gc0 = (float)gsl[0];   gc1 = (float)gsl[256];
            gc2 = (float)gsl[512]; gc3 = (float)gsl[768];
        }

        for (int l = 0; l < CH; l++) {
            float gn0 = 0.f, gn1 = 0.f, gn2 = 0.f, gn3 = 0.f;
            if (hh == 1 && l < CH - 1) {
                const _Float16* gp = gsl + (size_t)(l + 1) * BB * H4;
                gn0 = (float)gp[0];   gn1 = (float)gp[256];
                gn2 = (float)gp[512]; gn3 = (float)gp[768];
            }

            const uint4* hp4 = (const uint4*)(hlb + p * 272) + hh * 16;
            float a0 = 0.f, a1 = 0.f, a2 = 0.f, a3 = 0.f;

            // all 16 h quads x 4 resident weight quads each
#pragma unroll
            for (int j = 0; j < 16; j++) {
                uint4 hq = hp4[j];
#pragma unroll
                for (int u = 0; u < 4; u++) {
                    half2v hv = __builtin_bit_cast(half2v, hq[u]);
                    uint4 w = w4[4 * j + u];
                    a0 = fdot2_(w.x, hv, a0);
                    a1 = fdot2_(w.y, hv, a1);
                    a2 = fdot2_(w.z, hv, a2);
                    a3 = fdot2_(w.w, hv, a3);
                }
            }

            if (hh == 1) {
                float4 vv = make_float4(a0 + gc0, a1 + gc1, a2 + gc2, a3 + gc3);
                *(float4*)&pre[tau * 4] = vv;
            }
            __syncthreads();

            if (hh == 0) {
                float4 po = *(const float4*)&pre[tau * 4];
                float ig = fsig_(a0 + po.x);
                float fg = fsig_(a1 + po.y);
                float gg = ftanh_(a2 + po.z);
                float og = fsig_(a3 + po.w);
                c_ = fg * c_ + ig * gg;
                float h = og * ftanh_(c_);
                lastH = h;
                if (!isL2) {
                    int tc = ch * CH + l;
                    h1c[((size_t)b * TT + tc) * HH + tau] = (_Float16)h;
                }
                hlb[(p ^ 1) * 272 + tau] = (_Float16)h;
            }
            __syncthreads();
            p ^= 1;
            gc0 = gn0; gc1 = gn1; gc2 = gn2; gc3 = gn3;
        }

        if (tid == 0) {
            if (!isL2) __builtin_amdgcn_fence(__ATOMIC_RELEASE, "agent");
            __hip_atomic_store(&fOut[b].v, (unsigned)(ch + 1),
                               __ATOMIC_RELAXED, __HIP_MEMORY_SCOPE_AGENT);
        }
    }

    if (hh == 0) {
        cst[b * HH + tau] = c_;
        hst[b * HH + tau] = lastH;
    }
}

// ---------------------------------------------------------------------------
__global__ void fc_kernel(const float* __restrict__ h2,
                          const float* __restrict__ Wfc,
                          const float* __restrict__ bfc,
                          float* __restrict__ out)
{
    __shared__ float hs[256];
    int b = blockIdx.x, tid = threadIdx.x;
    hs[tid] = h2[b * HH + tid];
    __syncthreads();
    if (tid < NC) {
        float s = bfc[tid];
        for (int k = 0; k < 256; k++) s += hs[k] * Wfc[tid * 256 + k];
        out[b * NC + tid] = s;
    }
}

// ---------------------------------------------------------------------------
extern "C" void kernel_launch(void* const* d_in, const int* in_sizes, int n_in,
                              void* d_out, int out_size, void* d_ws, size_t ws_size,
                              hipStream_t stream)
{
    const float* x    = (const float*)d_in[0];
    const float* Wih0 = (const float*)d_in[1];
    const float* Whh0 = (const float*)d_in[2];
    const float* bih0 = (const float*)d_in[3];
    const float* bhh0 = (const float*)d_in[4];
    const float* Wih1 = (const float*)d_in[5];
    const float* Whh1 = (const float*)d_in[6];
    const float* bih1 = (const float*)d_in[7];
    const float* bhh1 = (const float*)d_in[8];
    const float* Wfc  = (const float*)d_in[9];
    const float* bfc  = (const float*)d_in[10];

    const size_t x16_b  = (size_t)BB * TT * HH * 2;      // 67.1 MB
    const size_t h1c_b  = x16_b;                          // 67.1 MB
    const size_t gxr_b  = (size_t)NR * CH * BB * H4 * 2;  // 33.6 MB
    const size_t w16_b  = (size_t)H4 * HH * 2;
    const size_t wpk_b  = (size_t)128 * 256 * 16;
    const size_t st_b   = (size_t)4 * BB * HH * 4;

    char* pp = (char*)d_ws;
    _Float16* x16  = (_Float16*)pp;  pp += x16_b;
    _Float16* h1c  = (_Float16*)pp;  pp += h1c_b;
    _Float16* gx1r = (_Float16*)pp;  pp += gxr_b;
    _Float16* gx2r = (_Float16*)pp;  pp += gxr_b;
    _Float16* w16a = (_Float16*)pp;  pp += w16_b;
    _Float16* w16b = (_Float16*)pp;  pp += w16_b;
    uint4*    wpk0 = (uint4*)pp;     pp += wpk_b;
    uint4*    wpk1 = (uint4*)pp;     pp += wpk_b;
    float*    hs1  = (float*)pp;
    float*    cs1  = hs1 + BB * HH;
    float*    hs2  = cs1 + BB * HH;
    float*    cs2  = hs2 + BB * HH;
    pp += st_b;
    Line* fG1 = (Line*)pp;
    Line* fL1 = fG1 + 64;
    Line* fG2 = fL1 + 64;
    Line* fL2 = fG2 + 64;

    // zero states + flags (contiguous)
    hipMemsetAsync(hs1, 0, st_b + 256 * sizeof(Line), stream);

    prep_w<<<128, 256, 0, stream>>>(Whh0, wpk0);
    prep_w<<<128, 256, 0, stream>>>(Whh1, wpk1);
    f32_to_f16<<<(BB * TT * HH / 8 + 255) / 256, 256, 0, stream>>>(x, x16, BB * TT * HH / 8);
    f32_to_f16<<<(H4 * HH / 8 + 255) / 256, 256, 0, stream>>>(Wih0, w16a, H4 * HH / 8);
    f32_to_f16<<<(H4 * HH / 8 + 255) / 256, 256, 0, stream>>>(Wih1, w16b, H4 * HH / 8);

    lstm_pipe<<<256, 512, 0, stream>>>(x16, w16a, w16b,
                                       bih0, bhh0, bih1, bhh1,
                                       wpk0, wpk1, gx1r, gx2r, h1c,
                                       hs1, cs1, hs2, cs2,
                                       fG1, fL1, fG2, fL2);

    fc_kernel<<<BB, 256, 0, stream>>>(hs2, Wfc, bfc, (float*)d_out);
}

// Round 17
// 3391.863 us; speedup vs baseline: 3.0451x; 3.0451x over previous
//
#include <hip/hip_runtime.h>
#include <hip/hip_bf16.h>

#define BB 64
#define TT 2048
#define HH 256
#define H4 1024
#define NC 10
#define CH 32            // steps per chunk
#define NCH (TT / CH)    // 64 chunks
#define NR 4             // gx ring slots

typedef _Float16 half2v __attribute__((ext_vector_type(2)));
typedef _Float16 half8  __attribute__((ext_vector_type(8)));
typedef float    f32x4  __attribute__((ext_vector_type(4)));

struct __align__(128) Line { unsigned v; unsigned pad[31]; };

__device__ __forceinline__ float fsig_(float x) {
    return __fdividef(1.f, 1.f + __expf(-x));
}
__device__ __forceinline__ float ftanh_(float x) {
    return 1.f - __fdividef(2.f, __expf(2.f * x) + 1.f);
}

__device__ __forceinline__ float fdot2_(unsigned wu, half2v hv, float acc) {
#if __has_builtin(__builtin_amdgcn_fdot2)
    return __builtin_amdgcn_fdot2(__builtin_bit_cast(half2v, wu), hv, acc, false);
#else
    half2v w = __builtin_bit_cast(half2v, wu);
    return acc + (float)w[0] * (float)hv[0] + (float)w[1] * (float)hv[1];
#endif
}

// wave-0 parallel poll of 64 flags; one acquire fence; releases whole WG.
__device__ __forceinline__ void wait_flags(Line* f, unsigned target, int tid) {
    if (tid < 64) {
        while (true) {
            unsigned v = __hip_atomic_load(&f[tid].v, __ATOMIC_RELAXED,
                                           __HIP_MEMORY_SCOPE_AGENT);
            if (__all(v >= target)) break;
            __builtin_amdgcn_s_sleep(2);
        }
        if (tid == 0)
            __builtin_amdgcn_fence(__ATOMIC_ACQUIRE, "agent");
    }
    __syncthreads();
}

// ---------------------------------------------------------------------------
__global__ void f32_to_f16(const float* __restrict__ in,
                           _Float16* __restrict__ out, int n8)
{
    int i = blockIdx.x * 256 + threadIdx.x;
    if (i >= n8) return;
    float4 v0 = ((const float4*)in)[2 * i];
    float4 v1 = ((const float4*)in)[2 * i + 1];
    half8 h;
    h[0] = (_Float16)v0.x; h[1] = (_Float16)v0.y;
    h[2] = (_Float16)v0.z; h[3] = (_Float16)v0.w;
    h[4] = (_Float16)v1.x; h[5] = (_Float16)v1.y;
    h[6] = (_Float16)v1.z; h[7] = (_Float16)v1.w;
    ((half8*)out)[i] = h;
}

// ---------------------------------------------------------------------------
__global__ void prep_w(const float* __restrict__ W, uint4* __restrict__ out)
{
    const int k2 = blockIdx.x, t = threadIdx.x;
    unsigned q4[4];
#pragma unroll
    for (int q = 0; q < 4; q++) {
        const float* wr = W + (size_t)(q * 256 + t) * 256 + 2 * k2;
        union { _Float16 h[2]; unsigned u; } cv;
        cv.h[0] = (_Float16)wr[0];
        cv.h[1] = (_Float16)wr[1];
        q4[q] = cv.u;
    }
    out[(size_t)k2 * 256 + t] = make_uint4(q4[0], q4[1], q4[2], q4[3]);
}

// ---------------------------------------------------------------------------
// 4-role pipelined persistent kernel, 256 WGs x 512 threads (R15 topology).
// gx stored GATE-INTERLEAVED: gx[tc][b][u*4+q] so the rec consumer loads one
// uint2 (4 halves) per step instead of 4 strided 2B loads.
// CH=32 halves pipeline lag. Rec engine: 48 resident quads + 16 LDS slices
// (R15-proven; 64 quads exceeds the 256 reg/wave unified budget -> R16 spill).
// gemm worker: WG sub covers tc = sub&31, n-half = (sub>>5)*512, one pass.
// ---------------------------------------------------------------------------
__global__ __launch_bounds__(512, 1)
void lstm_pipe(const _Float16* __restrict__ x16,
               const _Float16* __restrict__ w16a, const _Float16* __restrict__ w16b,
               const float* __restrict__ bih0, const float* __restrict__ bhh0,
               const float* __restrict__ bih1, const float* __restrict__ bhh1,
               const uint4* __restrict__ wpk0, const uint4* __restrict__ wpk1,
               _Float16* __restrict__ gx1r, _Float16* __restrict__ gx2r,
               _Float16* __restrict__ h1c,
               float* __restrict__ hs1, float* __restrict__ cs1,
               float* __restrict__ hs2, float* __restrict__ cs2,
               Line* __restrict__ fG1, Line* __restrict__ fL1,
               Line* __restrict__ fG2, Line* __restrict__ fL2)
{
    __shared__ __align__(16) unsigned char pool[1088 + 4096 + 32 * 4096];
    _Float16* hlb = (_Float16*)pool;
    float*    pre = (float*)(pool + 1088);
    uint4*    wl  = (uint4*)(pool + 1088 + 4096);

    const int wg = blockIdx.x, tid = threadIdx.x;
    const int role = wg >> 6, sub = wg & 63;

    if (role == 1 || role == 2) {
        // ---------------- gemm worker ----------------
        const bool isG2 = (role == 2);
        const _Float16* A  = isG2 ? h1c  : x16;
        const _Float16* Wm = isG2 ? w16b : w16a;
        const float* b1 = isG2 ? bih1 : bih0;
        const float* b2 = isG2 ? bhh1 : bhh0;
        _Float16* outr  = isG2 ? gx2r : gx1r;
        Line* fOut      = isG2 ? fG2  : fG1;

        const int v = tid >> 6, lane = tid & 63;
        const int lrow = lane & 15, lkg = lane >> 4;
        const int rquad = v & 3, nqh = v >> 2;
        const int tcl = sub & 31;               // tc within chunk
        const int n0 = (sub >> 5) * 512 + nqh * 256;

        const _Float16* wrow0 = Wm + (size_t)(n0 + lrow) * 256 + lkg * 8;

        for (int c = 0; c < NCH; c++) {
            if (isG2) {
                wait_flags(fL1, (unsigned)(c + 1), tid);
                if (c >= NR) wait_flags(fL2, (unsigned)(c - (NR - 1)), tid);
            } else {
                if (c >= NR) wait_flags(fL1, (unsigned)(c - (NR - 1)), tid);
            }
            const int tc = c * CH + tcl;
            const int slot = c % NR;
            const _Float16* arow =
                A + ((size_t)(rquad * 16 + lrow) * TT + tc) * 256 + lkg * 8;

            f32x4 acc[16];
#pragma unroll
            for (int j = 0; j < 16; j++) acc[j] = (f32x4)(0.f);
#pragma unroll
            for (int k0 = 0; k0 < 256; k0 += 32) {
                half8 a = *(const half8*)(arow + k0);
#pragma unroll
                for (int j = 0; j < 16; j++) {
                    half8 bf = *(const half8*)(wrow0 + (size_t)j * 16 * 256 + k0);
                    acc[j] = __builtin_amdgcn_mfma_f32_16x16x32_f16(a, bf, acc[j], 0, 0, 0);
                }
            }
            const int bout = rquad * 16 + lkg * 4;
#pragma unroll
            for (int j = 0; j < 16; j++) {
                int n = n0 + j * 16 + lrow;
                float bsum = b1[n] + b2[n];
                int u = n & 255, q = n >> 8;       // gate-interleaved target
#pragma unroll
                for (int r = 0; r < 4; r++) {
                    outr[((size_t)(slot * CH + tcl) * BB + bout + r) * H4 + u * 4 + q] =
                        (_Float16)(acc[j][r] + bsum);
                }
            }
            __syncthreads();   // drain this WG's stores
            if (tid == 0) {
                __builtin_amdgcn_fence(__ATOMIC_RELEASE, "agent");
                __hip_atomic_store(&fOut[sub].v, (unsigned)(c + 1),
                                   __ATOMIC_RELAXED, __HIP_MEMORY_SCOPE_AGENT);
            }
        }
        return;
    }

    // ---------------- recurrence (role 0 = L1, role 3 = L2) ----------------
    const bool isL2 = (role == 3);
    const uint4* wpk = isL2 ? wpk1 : wpk0;
    const _Float16* gxr = isL2 ? gx2r : gx1r;
    float* hst = isL2 ? hs2 : hs1;
    float* cst = isL2 ? cs2 : cs1;
    Line* fIn  = isL2 ? fG2 : fG1;
    Line* fOut = isL2 ? fL2 : fL1;
    const int b = sub;
    const int tau = tid & 255, hh = tid >> 8;

    // stage LDS weight slices: s[0,16) -> k2 48+s (hh0), s[16,32) -> 96+s (hh1)
#pragma unroll
    for (int m = 0; m < 16; m++) {
        int e = m * 512 + tid;
        int s = e >> 8, tp = e & 255;
        int k2g = (s < 16) ? (48 + s) : (96 + s);
        wl[e] = wpk[(size_t)k2g * 256 + tp];
    }

    uint4 w4[48];
    {
        const volatile unsigned* wv = (const volatile unsigned*)wpk;
#pragma unroll
        for (int r = 0; r < 48; r++) {
            size_t base = ((size_t)(hh * 64 + r) * 256 + tau) * 4;
            w4[r].x = wv[base + 0];
            w4[r].y = wv[base + 1];
            w4[r].z = wv[base + 2];
            w4[r].w = wv[base + 3];
        }
    }

    const uint4* wbase = wl + hh * 4096 + tau;

    float c_ = 0.f, lastH = 0.f;
    if (hh == 0) {
        c_ = cst[b * HH + tau];
        lastH = hst[b * HH + tau];
        hlb[tau] = (_Float16)lastH;
    }
    __syncthreads();

    int p = 0;
    for (int ch = 0; ch < NCH; ch++) {
        wait_flags(fIn, (unsigned)(ch + 1), tid);
        // gate-interleaved gx: 4 halves per (b,tau) at one address
        const _Float16* gsl = gxr + (size_t)(ch % NR) * CH * BB * H4
                            + (size_t)b * H4 + tau * 4;
        uint2 gq = make_uint2(0, 0);
        if (hh == 1) gq = *(const uint2*)gsl;

        for (int l = 0; l < CH; l++) {
            uint2 gqn = make_uint2(0, 0);
            if (hh == 1 && l < CH - 1)
                gqn = *(const uint2*)(gsl + (size_t)(l + 1) * BB * H4);

            const uint4* hp4 = (const uint4*)(hlb + p * 272) + hh * 16;
            float a0 = 0.f, a1 = 0.f, a2 = 0.f, a3 = 0.f;

#pragma unroll
            for (int j = 0; j < 12; j++) {
                uint4 hq = hp4[j];
#pragma unroll
                for (int u = 0; u < 4; u++) {
                    half2v hv = __builtin_bit_cast(half2v, hq[u]);
                    uint4 w = w4[4 * j + u];
                    a0 = fdot2_(w.x, hv, a0);
                    a1 = fdot2_(w.y, hv, a1);
                    a2 = fdot2_(w.z, hv, a2);
                    a3 = fdot2_(w.w, hv, a3);
                }
            }
#pragma unroll
            for (int j = 12; j < 16; j++) {
                uint4 hq = hp4[j];
#pragma unroll
                for (int u = 0; u < 4; u++) {
                    uint4 w = wbase[(4 * (j - 12) + u) * 256];
                    half2v hv = __builtin_bit_cast(half2v, hq[u]);
                    a0 = fdot2_(w.x, hv, a0);
                    a1 = fdot2_(w.y, hv, a1);
                    a2 = fdot2_(w.z, hv, a2);
                    a3 = fdot2_(w.w, hv, a3);
                }
            }

            if (hh == 1) {
                half2v glo = __builtin_bit_cast(half2v, gq.x);
                half2v ghi = __builtin_bit_cast(half2v, gq.y);
                float4 vv = make_float4(a0 + (float)glo[0], a1 + (float)glo[1],
                                        a2 + (float)ghi[0], a3 + (float)ghi[1]);
                *(float4*)&pre[tau * 4] = vv;
            }
            __syncthreads();

            if (hh == 0) {
                float4 po = *(const float4*)&pre[tau * 4];
                float ig = fsig_(a0 + po.x);
                float fg = fsig_(a1 + po.y);
                float gg = ftanh_(a2 + po.z);
                float og = fsig_(a3 + po.w);
                c_ = fg * c_ + ig * gg;
                float h = og * ftanh_(c_);
                lastH = h;
                if (!isL2) {
                    int tc = ch * CH + l;
                    h1c[((size_t)b * TT + tc) * HH + tau] = (_Float16)h;
                }
                hlb[(p ^ 1) * 272 + tau] = (_Float16)h;
            }
            __syncthreads();
            p ^= 1;
            gq = gqn;
        }

        if (tid == 0) {
            if (!isL2) __builtin_amdgcn_fence(__ATOMIC_RELEASE, "agent");
            __hip_atomic_store(&fOut[b].v, (unsigned)(ch + 1),
                               __ATOMIC_RELAXED, __HIP_MEMORY_SCOPE_AGENT);
        }
    }

    if (hh == 0) {
        cst[b * HH + tau] = c_;
        hst[b * HH + tau] = lastH;
    }
}

// ---------------------------------------------------------------------------
__global__ void fc_kernel(const float* __restrict__ h2,
                          const float* __restrict__ Wfc,
                          const float* __restrict__ bfc,
                          float* __restrict__ out)
{
    __shared__ float hs[256];
    int b = blockIdx.x, tid = threadIdx.x;
    hs[tid] = h2[b * HH + tid];
    __syncthreads();
    if (tid < NC) {
        float s = bfc[tid];
        for (int k = 0; k < 256; k++) s += hs[k] * Wfc[tid * 256 + k];
        out[b * NC + tid] = s;
    }
}

// ---------------------------------------------------------------------------
extern "C" void kernel_launch(void* const* d_in, const int* in_sizes, int n_in,
                              void* d_out, int out_size, void* d_ws, size_t ws_size,
                              hipStream_t stream)
{
    const float* x    = (const float*)d_in[0];
    const float* Wih0 = (const float*)d_in[1];
    const float* Whh0 = (const float*)d_in[2];
    const float* bih0 = (const float*)d_in[3];
    const float* bhh0 = (const float*)d_in[4];
    const float* Wih1 = (const float*)d_in[5];
    const float* Whh1 = (const float*)d_in[6];
    const float* bih1 = (const float*)d_in[7];
    const float* bhh1 = (const float*)d_in[8];
    const float* Wfc  = (const float*)d_in[9];
    const float* bfc  = (const float*)d_in[10];

    const size_t x16_b  = (size_t)BB * TT * HH * 2;      // 67.1 MB
    const size_t h1c_b  = x16_b;                          // 67.1 MB
    const size_t gxr_b  = (size_t)NR * CH * BB * H4 * 2;  // 16.8 MB
    const size_t w16_b  = (size_t)H4 * HH * 2;
    const size_t wpk_b  = (size_t)128 * 256 * 16;
    const size_t st_b   = (size_t)4 * BB * HH * 4;

    char* pp = (char*)d_ws;
    _Float16* x16  = (_Float16*)pp;  pp += x16_b;
    _Float16* h1c  = (_Float16*)pp;  pp += h1c_b;
    _Float16* gx1r = (_Float16*)pp;  pp += gxr_b;
    _Float16* gx2r = (_Float16*)pp;  pp += gxr_b;
    _Float16* w16a = (_Float16*)pp;  pp += w16_b;
    _Float16* w16b = (_Float16*)pp;  pp += w16_b;
    uint4*    wpk0 = (uint4*)pp;     pp += wpk_b;
    uint4*    wpk1 = (uint4*)pp;     pp += wpk_b;
    float*    hs1  = (float*)pp;
    float*    cs1  = hs1 + BB * HH;
    float*    hs2  = cs1 + BB * HH;
    float*    cs2  = hs2 + BB * HH;
    pp += st_b;
    Line* fG1 = (Line*)pp;
    Line* fL1 = fG1 + 64;
    Line* fG2 = fL1 + 64;
    Line* fL2 = fG2 + 64;

    // zero states + flags (contiguous)
    hipMemsetAsync(hs1, 0, st_b + 256 * sizeof(Line), stream);

    prep_w<<<128, 256, 0, stream>>>(Whh0, wpk0);
    prep_w<<<128, 256, 0, stream>>>(Whh1, wpk1);
    f32_to_f16<<<(BB * TT * HH / 8 + 255) / 256, 256, 0, stream>>>(x, x16, BB * TT * HH / 8);
    f32_to_f16<<<(H4 * HH / 8 + 255) / 256, 256, 0, stream>>>(Wih0, w16a, H4 * HH / 8);
    f32_to_f16<<<(H4 * HH / 8 + 255) / 256, 256, 0, stream>>>(Wih1, w16b, H4 * HH / 8);

    lstm_pipe<<<256, 512, 0, stream>>>(x16, w16a, w16b,
                                       bih0, bhh0, bih1, bhh1,
                                       wpk0, wpk1, gx1r, gx2r, h1c,
                                       hs1, cs1, hs2, cs2,
                                       fG1, fL1, fG2, fL2);

    fc_kernel<<<BB, 256, 0, stream>>>(hs2, Wfc, bfc, (float*)d_out);
}